// Round 4
// baseline (149.601 us; speedup 1.0000x reference)
//
#include <hip/hip_runtime.h>
#include <hip/hip_bf16.h>

#define NB    2048
#define NUMK  128
#define NE    1024
#define HID   32
#define ROWLEN (NUMK + NE + 2)
#define NSLOT (NE + NUMK)        // 1152 slots: edges + self-loops (some flagged extra)
#define ASTRIDE 136              // bf16 elems per Â row (128 + 8 pad, 272 B = 16B-aligned)
#define A1STRIDE 40              // bf16 elems per a1/W2T row (32 + 8 pad, 80 B = 16B-aligned)

// slot encoding: eid(11)<<21 | flag(1)<<20 | dst(7)<<13 | aux(13)
//   primary slot: aux = src            (unique (dst,src) pair)
//   extra  slot: aux = target slot idx (duplicate pair: weight merges into target)
//   eid == 1024 means "self-loop", weight 1.0

using s8  = __attribute__((ext_vector_type(8))) short;   // 8 bf16 (A/B frag)
using f4  = __attribute__((ext_vector_type(4))) float;   // C/D frag
using fl4 = __attribute__((ext_vector_type(4))) float;

static __device__ __forceinline__ unsigned short f2bf(float f) {
    unsigned u = __float_as_uint(f);
    unsigned r = (u + 0x7fffu + ((u >> 16) & 1u)) >> 16;   // RNE
    return (unsigned short)r;
}

// ---------------------------------------------------------------------------
// Setup (once per launch): CSR-by-dst with self-loops folded in, then per-row
// duplicate detection. Emits flat slotArr[NSLOT] with the encoding above.
// ---------------------------------------------------------------------------
__global__ __launch_bounds__(1024) void build_csr_kernel(
    const int* __restrict__ ei,
    unsigned* __restrict__ slotArr)      // [NSLOT]
{
    __shared__ unsigned cnt[NUMK], roff[NUMK + 1], cur[NUMK], incl[NUMK];
    __shared__ unsigned pk[NSLOT];       // temp: sr | (eid<<16)
    const int t = threadIdx.x;

    if (t < NUMK) cnt[t] = 1u;           // self slot
    __syncthreads();
    const int dst = ei[NE + t] & (NUMK - 1);
    atomicAdd(&cnt[dst], 1u);
    __syncthreads();

    // exclusive scan over 128 counts (two 64-lane wave scans)
    if (t < NUMK) {
        unsigned v = cnt[t];
        #pragma unroll
        for (int d = 1; d < 64; d <<= 1) {
            unsigned u = __shfl_up(v, d, 64);
            if ((t & 63) >= d) v += u;
        }
        incl[t] = v;
    }
    __syncthreads();
    if (t < NUMK) {
        const unsigned base = (t >= 64) ? incl[63] : 0u;
        const unsigned off  = base + incl[t] - cnt[t];
        roff[t] = off; cur[t] = off;
    }
    if (t == 0) roff[NUMK] = (unsigned)NSLOT;
    __syncthreads();

    {
        const int src = ei[t] & (NUMK - 1);
        const unsigned pos = atomicAdd(&cur[dst], 1u);
        pk[pos] = (unsigned)src | ((unsigned)t << 16);
    }
    if (t < NUMK) {
        const unsigned pos = atomicAdd(&cur[t], 1u);
        pk[pos] = (unsigned)t | (1024u << 16);       // self: eid = 1024
    }
    __syncthreads();

    // per-row dedup: first occurrence of each src is primary; later ones are
    // extras targeting the first occurrence's slot index.
    if (t < NUMK) {
        const unsigned k0 = roff[t], k1 = roff[t + 1];
        for (unsigned k = k0; k < k1; ++k) {
            const unsigned u  = pk[k];
            const unsigned sr = u & 127u, eid = u >> 16;
            unsigned flag = 0u, aux = sr;
            for (unsigned j = k0; j < k; ++j) {
                if ((pk[j] & 127u) == sr) { flag = 1u; aux = j; break; }
            }
            slotArr[k] = (eid << 21) | (flag << 20) | ((unsigned)t << 13) | aux;
        }
    }
}

// ---------------------------------------------------------------------------
// Main: one block (256 thr = 4 waves) per graph. No per-row loops anywhere:
// all sparse phases are slot-parallel (<=5 register-resident slots/thread).
//  P1 stage + zero       P2 w-gather + deg atomics    P2b dup-weight merge
//  P3 dinv (in place)    P4 norms -> Â bf16 write + a0 fp32 atomics
//  P6 a1 = Â @ x1 (MFMA, x1 on the fly)   P5' a1 -> LDS bf16
//  P7 x2 = relu(a1@W2+b2) (MFMA) + s = x2@W3 (shfl)
//  P8 out-agg fp32 atomics               P9 coalesced store
// ---------------------------------------------------------------------------
__global__ __launch_bounds__(256) void gcn_main_kernel(
    const float* __restrict__ Hx,
    const float* __restrict__ W1, const float* __restrict__ b1,
    const float* __restrict__ W2, const float* __restrict__ b2,
    const float* __restrict__ W3, const float* __restrict__ b3,
    const unsigned* __restrict__ slotArr_g,
    float* __restrict__ out)
{
    __shared__ short Ab[NUMK * ASTRIDE];        // 34816 B  (Â, bf16)
    __shared__ float wslot[NSLOT];              //  4608 B  (w, then norm)
    __shared__ short W2T[HID * A1STRIDE];       //  2560 B
    __shared__ short a1bf[NUMK * A1STRIDE];     // 10240 B
    __shared__ float degv[NUMK];                //   512 B  deg -> dinv -> sbuf
    __shared__ float pbuf[NUMK];                //   512 B  p    -> outacc
    __shared__ float a0s[NUMK];                 //   512 B
    __shared__ float w1s[HID], b1s[HID], b2s[HID], w3s[HID];   // 512 B
    // total 54,272 B -> 3 blocks/CU

    const int tid = threadIdx.x;
    const float* rowp = Hx + (size_t)blockIdx.x * ROWLEN;

    // ---- P1: zero + stage ----
    for (int t2 = tid; t2 < (NUMK * ASTRIDE) / 8; t2 += 256)
        *(s8*)&Ab[t2 * 8] = (s8)0;
    if (tid < NUMK) { pbuf[tid] = rowp[tid]; degv[tid] = 0.f; a0s[tid] = 0.f; }
    for (int t2 = tid; t2 < HID * HID; t2 += 256) {
        const int k = t2 >> 5, n = t2 & 31;
        W2T[n * A1STRIDE + k] = (short)f2bf(W2[t2]);
    }
    if (tid < HID) {
        w1s[tid] = W1[tid]; b1s[tid] = b1[tid];
        b2s[tid] = b2[tid]; w3s[tid] = W3[tid];
    }

    // my slots: registers for the whole kernel (coalesced load, independent)
    unsigned su[5]; float sw[5];
    #pragma unroll
    for (int k = 0; k < 5; ++k) {
        const int s = tid + (k << 8);
        su[k] = (s < NSLOT) ? slotArr_g[s] : 0u;
    }
    // w gather (independent global loads; eid>=1024 -> self weight 1)
    #pragma unroll
    for (int k = 0; k < 5; ++k) {
        const int s = tid + (k << 8);
        if (s < NSLOT) {
            const unsigned eid = su[k] >> 21;
            sw[k] = (eid >= 1024u) ? 1.0f : rowp[NUMK + eid];
        }
    }
    __syncthreads();

    // ---- P2: wslot + degree (all slots, incl. extras) ----
    #pragma unroll
    for (int k = 0; k < 5; ++k) {
        const int s = tid + (k << 8);
        if (s < NSLOT) {
            wslot[s] = sw[k];
            atomicAdd(&degv[(su[k] >> 13) & 127u], sw[k]);
        }
    }
    __syncthreads();

    // ---- P2b: merge duplicate weights into primary slots ----
    #pragma unroll
    for (int k = 0; k < 5; ++k) {
        const int s = tid + (k << 8);
        if (s < NSLOT && ((su[k] >> 20) & 1u))
            atomicAdd(&wslot[su[k] & 0x1FFFu], sw[k]);
    }
    __syncthreads();

    // ---- P3: dinv in place (deg >= 1 always: self weight 1) ----
    if (tid < NUMK) degv[tid] = rsqrtf(degv[tid]);
    __syncthreads();

    // ---- P4: norms -> Â (pure bf16 writes, unique pairs) + a0 = Â·p (fp32) ----
    #pragma unroll
    for (int k = 0; k < 5; ++k) {
        const int s = tid + (k << 8);
        if (s < NSLOT && !((su[k] >> 20) & 1u)) {
            const unsigned u  = su[k];
            const int sr = (int)(u & 127u);
            const int dr = (int)((u >> 13) & 127u);
            const float nv = degv[dr] * degv[sr] * wslot[s];
            Ab[dr * ASTRIDE + sr] = (short)f2bf(nv);
            wslot[s] = nv;                               // reuse as norm
            atomicAdd(&a0s[dr], nv * pbuf[sr]);
        }
    }
    __syncthreads();

    // zero outacc (aliases pbuf; pbuf dead after P4)
    float* outacc = pbuf;
    if (tid < NUMK) outacc[tid] = 0.f;

    // ---- P6: a1 = Â @ x1, x1[k][j] = relu(a0[k]*w1[j]+b1[j]) on the fly ----
    const int wv = tid >> 6;          // wave 0..3 -> rows [32wv, 32wv+32)
    const int l  = tid & 15;          // n index within 16-tile
    const int q  = (tid & 63) >> 4;   // quad 0..3 -> k-chunk / C-row group
    f4 acc[2][2] = {{{0.f,0.f,0.f,0.f},{0.f,0.f,0.f,0.f}},
                    {{0.f,0.f,0.f,0.f},{0.f,0.f,0.f,0.f}}};
    {
        const float w1a = w1s[l],      b1a = b1s[l];
        const float w1b = w1s[l + 16], b1b = b1s[l + 16];
        #pragma unroll
        for (int ks = 0; ks < 4; ++ks) {
            const int kb = 32 * ks + 8 * q;
            const s8 Am0 = *(const s8*)&Ab[(32 * wv      + l) * ASTRIDE + kb];
            const s8 Am1 = *(const s8*)&Ab[(32 * wv + 16 + l) * ASTRIDE + kb];
            const fl4 p0 = *(const fl4*)&a0s[kb];
            const fl4 p1 = *(const fl4*)&a0s[kb + 4];
            union { s8 v; unsigned u[4]; } B0, B1;
            #pragma unroll
            for (int e = 0; e < 4; ++e) {
                const float a0e = (e < 2) ? p0[2*e]     : p1[2*e - 4];
                const float a1e = (e < 2) ? p0[2*e + 1] : p1[2*e - 3];
                float xa0 = fmaf(a0e, w1a, b1a); xa0 = fmaxf(xa0, 0.f);
                float xa1 = fmaf(a1e, w1a, b1a); xa1 = fmaxf(xa1, 0.f);
                float xb0 = fmaf(a0e, w1b, b1b); xb0 = fmaxf(xb0, 0.f);
                float xb1 = fmaf(a1e, w1b, b1b); xb1 = fmaxf(xb1, 0.f);
                B0.u[e] = (unsigned)f2bf(xa0) | ((unsigned)f2bf(xa1) << 16);
                B1.u[e] = (unsigned)f2bf(xb0) | ((unsigned)f2bf(xb1) << 16);
            }
            acc[0][0] = __builtin_amdgcn_mfma_f32_16x16x32_bf16(Am0, B0.v, acc[0][0], 0, 0, 0);
            acc[0][1] = __builtin_amdgcn_mfma_f32_16x16x32_bf16(Am0, B1.v, acc[0][1], 0, 0, 0);
            acc[1][0] = __builtin_amdgcn_mfma_f32_16x16x32_bf16(Am1, B0.v, acc[1][0], 0, 0, 0);
            acc[1][1] = __builtin_amdgcn_mfma_f32_16x16x32_bf16(Am1, B1.v, acc[1][1], 0, 0, 0);
        }
    }

    // ---- P5': a1 (C layout) -> LDS bf16 (own wave's rows only) ----
    #pragma unroll
    for (int mt = 0; mt < 2; ++mt)
        #pragma unroll
        for (int nt = 0; nt < 2; ++nt)
            #pragma unroll
            for (int r = 0; r < 4; ++r) {
                const int i = 32 * wv + 16 * mt + 4 * q + r;
                const int j = 16 * nt + l;
                a1bf[i * A1STRIDE + j] = (short)f2bf(acc[mt][nt][r]);
            }

    // ---- P7: x2 = relu(a1 @ W2 + b2); s = x2 @ W3 via shfl; sbuf = degv ----
    float* sbuf = degv;            // dinv dead after P4
    {
        f4 ac2[2][2] = {{{0.f,0.f,0.f,0.f},{0.f,0.f,0.f,0.f}},
                        {{0.f,0.f,0.f,0.f},{0.f,0.f,0.f,0.f}}};
        const s8 A0  = *(const s8*)&a1bf[(32 * wv      + l) * A1STRIDE + 8 * q];
        const s8 A1  = *(const s8*)&a1bf[(32 * wv + 16 + l) * A1STRIDE + 8 * q];
        const s8 Bw0 = *(const s8*)&W2T[(l)      * A1STRIDE + 8 * q];
        const s8 Bw1 = *(const s8*)&W2T[(16 + l) * A1STRIDE + 8 * q];
        ac2[0][0] = __builtin_amdgcn_mfma_f32_16x16x32_bf16(A0, Bw0, ac2[0][0], 0, 0, 0);
        ac2[0][1] = __builtin_amdgcn_mfma_f32_16x16x32_bf16(A0, Bw1, ac2[0][1], 0, 0, 0);
        ac2[1][0] = __builtin_amdgcn_mfma_f32_16x16x32_bf16(A1, Bw0, ac2[1][0], 0, 0, 0);
        ac2[1][1] = __builtin_amdgcn_mfma_f32_16x16x32_bf16(A1, Bw1, ac2[1][1], 0, 0, 0);

        const float b2a = b2s[l], b2b = b2s[l + 16];
        const float w3a = w3s[l], w3b = w3s[l + 16];
        #pragma unroll
        for (int mt = 0; mt < 2; ++mt)
            #pragma unroll
            for (int r = 0; r < 4; ++r) {
                const float v0 = fmaxf(ac2[mt][0][r] + b2a, 0.f);
                const float v1 = fmaxf(ac2[mt][1][r] + b2b, 0.f);
                float sv = v0 * w3a + v1 * w3b;
                #pragma unroll
                for (int m = 1; m < 16; m <<= 1) sv += __shfl_xor(sv, m, 16);
                if (l == 0) sbuf[32 * wv + 16 * mt + 4 * q + r] = sv;
            }
    }
    __syncthreads();

    // ---- P8: out-agg = Â·s via fp32 atomics (norms cached in wslot) ----
    #pragma unroll
    for (int k = 0; k < 5; ++k) {
        const int s = tid + (k << 8);
        if (s < NSLOT && !((su[k] >> 20) & 1u)) {
            const unsigned u = su[k];
            atomicAdd(&outacc[(u >> 13) & 127u], wslot[s] * sbuf[u & 127u]);
        }
    }
    __syncthreads();

    // ---- P9: coalesced store ----
    if (tid < NUMK)
        out[(size_t)blockIdx.x * NUMK + tid] = outacc[tid] + b3[0];
}

extern "C" void kernel_launch(void* const* d_in, const int* in_sizes, int n_in,
                              void* d_out, int out_size, void* d_ws, size_t ws_size,
                              hipStream_t stream) {
    const float* Hx = (const float*)d_in[0];
    const int*   ei = (const int*)d_in[1];
    const float* W1 = (const float*)d_in[2];
    const float* b1 = (const float*)d_in[3];
    const float* W2 = (const float*)d_in[4];
    const float* b2 = (const float*)d_in[5];
    const float* W3 = (const float*)d_in[6];
    const float* b3 = (const float*)d_in[7];
    float* out = (float*)d_out;

    unsigned* slotArr = (unsigned*)d_ws;           // [NSLOT]

    build_csr_kernel<<<1, 1024, 0, stream>>>(ei, slotArr);
    gcn_main_kernel<<<NB, 256, 0, stream>>>(Hx, W1, b1, W2, b2, W3, b3,
                                            slotArr, out);
}

// Round 6
// 121.408 us; speedup vs baseline: 1.2322x; 1.2322x over previous
//
#include <hip/hip_runtime.h>
#include <hip/hip_bf16.h>

#define NB    2048
#define NUMK  128
#define NE    1024
#define HID   32
#define ROWLEN (NUMK + NE + 2)
#define CAP   32                 // padded slots per row
#define NPS   (NUMK * CAP)       // 4096 padded slots
#define ASTRIDE 136              // bf16 elems per Â row (128 + 8 pad)
#define A1STRIDE 40              // bf16 elems per a1/W2T row (32 + 8 pad)
#define WSELF 1024               // widx of self-loop weight (1.0)
#define WPAD  1025               // widx of pad weight (0.0)
#define NPASS 8                  // dup-merge passes

// padded slot encoding (19 bits): src(7) | widx(11)<<7 | primary(1)<<18
// dup-merge entry: eid_primary(11) | eid_dup(11)<<11  (wshp[p] += wshp[d])

using s8  = __attribute__((ext_vector_type(8))) short;   // 8 bf16 (A/B frag)
using f4  = __attribute__((ext_vector_type(4))) float;   // C/D frag
using fl4 = __attribute__((ext_vector_type(4))) float;

static __device__ __forceinline__ unsigned short f2bf(float f) {
    unsigned u = __float_as_uint(f);
    unsigned r = (u + 0x7fffu + ((u >> 16) & 1u)) >> 16;   // RNE
    return (unsigned short)r;
}

// ---------------------------------------------------------------------------
// Setup (once per launch): CSR by dst, then per-row dedup + pad to CAP slots.
// Emits pslot[NPS], dcnt[NPASS], dent[NPASS*128].
// ---------------------------------------------------------------------------
__global__ __launch_bounds__(1024) void build_csr_kernel(
    const int* __restrict__ ei,
    unsigned* __restrict__ pslot_g,    // [NPS]
    unsigned* __restrict__ dcnt_g,     // [NPASS]
    unsigned* __restrict__ dent_g)     // [NPASS*128]
{
    __shared__ unsigned cnt[NUMK], roff[NUMK + 1], cur[NUMK], incl[NUMK];
    __shared__ unsigned pk[NE];                 // src | (eid<<16), CSR by dst
    __shared__ unsigned psl[NUMK][CAP];         // slot + dupcnt in bits 19+
    __shared__ unsigned dc[NPASS];
    const int t = threadIdx.x;

    if (t < NUMK) cnt[t] = 0u;
    if (t < NPASS) dc[t] = 0u;
    __syncthreads();
    const int dst = ei[NE + t] & (NUMK - 1);
    atomicAdd(&cnt[dst], 1u);
    __syncthreads();

    if (t < NUMK) {                              // exclusive scan (2 wave scans)
        unsigned v = cnt[t];
        #pragma unroll
        for (int d = 1; d < 64; d <<= 1) {
            unsigned u = __shfl_up(v, d, 64);
            if ((t & 63) >= d) v += u;
        }
        incl[t] = v;
    }
    __syncthreads();
    if (t < NUMK) {
        const unsigned base = (t >= 64) ? incl[63] : 0u;
        const unsigned off  = base + incl[t] - cnt[t];
        roff[t] = off; cur[t] = off;
    }
    if (t == 0) roff[NUMK] = (unsigned)NE;
    __syncthreads();

    {
        const int src = ei[t] & (NUMK - 1);
        const unsigned pos = atomicAdd(&cur[dst], 1u);
        pk[pos] = (unsigned)src | ((unsigned)t << 16);
    }
    __syncthreads();

    // per-row pack + dedup (one thread per row; rows are tiny)
    if (t < NUMK) {
        const unsigned k0 = roff[t], k1 = roff[t + 1];
        int np = 0;
        for (unsigned k = k0; k < k1; ++k) {
            const unsigned u = pk[k];
            const unsigned s = u & 127u, eid = u >> 16;
            int j = -1;
            for (int i = 0; i < np; ++i)
                if ((psl[t][i] & 127u) == s) { j = i; break; }
            if (j >= 0) {
                const unsigned m = psl[t][j] >> 19;           // dup index
                psl[t][j] += (1u << 19);
                const unsigned pass = m < NPASS ? m : NPASS - 1;
                const unsigned idx = atomicAdd(&dc[pass], 1u);
                dent_g[pass * 128 + idx] =
                    ((psl[t][j] >> 7) & 0x7FFu) | (eid << 11);
            } else if (np < CAP) {
                psl[t][np++] = s | (eid << 7) | (1u << 18);
            }
        }
        // self-loop (weight 1): merge into an existing (t,t) edge if present
        int j = -1;
        for (int i = 0; i < np; ++i)
            if ((psl[t][i] & 127u) == (unsigned)t) { j = i; break; }
        if (j >= 0) {
            const unsigned m = psl[t][j] >> 19;
            psl[t][j] += (1u << 19);
            const unsigned pass = m < NPASS ? m : NPASS - 1;
            const unsigned idx = atomicAdd(&dc[pass], 1u);
            dent_g[pass * 128 + idx] =
                ((psl[t][j] >> 7) & 0x7FFu) | ((unsigned)WSELF << 11);
        } else if (np < CAP) {
            psl[t][np++] = (unsigned)t | ((unsigned)WSELF << 7) | (1u << 18);
        }
        for (int i = np; i < CAP; ++i)
            psl[t][i] = ((unsigned)WPAD << 7);               // pad: w=0, not primary
    }
    __syncthreads();

    for (int i = t; i < NPS; i += 1024)
        pslot_g[i] = psl[i >> 5][i & 31] & 0x7FFFFu;
    if (t < NPASS) dcnt_g[t] = dc[t];
}

// ---------------------------------------------------------------------------
// Main: one block (256 thr = 4 waves) per graph. NO atomics, NO row-serial
// loops: 8 lanes per row x 4 slots per lane, shfl-butterfly reductions.
//  P0 stage (+ zero Â, su regs)
//  P3 dup-weight merge (MUST precede degree! R5 bug was this order)
//  P2 deg -> dinv (shfl)
//  P4 norms -> Â bf16 + a0 (shfl; nv kept in regs)
//  P6 a1 = Â @ x1 (MFMA, x1 on the fly)   P5' a1 -> LDS bf16
//  P7 x2 = relu(a1@W2+b2) (MFMA) + s = x2@W3 (shfl)
//  P8 out = Â·s (shfl, nv regs) -> global store
// ---------------------------------------------------------------------------
__global__ __launch_bounds__(256) void gcn_main_kernel(
    const float* __restrict__ Hx,
    const float* __restrict__ W1, const float* __restrict__ b1,
    const float* __restrict__ W2, const float* __restrict__ b2,
    const float* __restrict__ W3, const float* __restrict__ b3,
    const unsigned* __restrict__ pslot_g,
    const unsigned* __restrict__ dcnt_g,
    const unsigned* __restrict__ dent_g,
    float* __restrict__ out)
{
    __shared__ short Ab[NUMK * ASTRIDE];        // 34816 B (Â bf16)
    __shared__ float wshp[WPAD + 1];            //  4104 B (w; [1024]=1, [1025]=0)
    __shared__ short W2T[HID * A1STRIDE];       //  2560 B
    __shared__ short a1bf[NUMK * A1STRIDE];     // 10240 B
    __shared__ float degv[NUMK];                //   512 B (dinv; later sbuf)
    __shared__ float pbuf[NUMK];                //   512 B
    __shared__ float a0s[NUMK];                 //   512 B
    __shared__ float w1s[HID], b1s[HID], b2s[HID], w3s[HID];   // 512 B
    // total ~53.8 KB -> 3 blocks/CU

    const int tid = threadIdx.x;
    const int grp = tid >> 3;        // row group 0..31
    const int l8  = tid & 7;         // lane within row group
    const float* rowp = Hx + (size_t)blockIdx.x * ROWLEN;

    // ---- P0: global loads first (latency overlap), then LDS staging ----
    unsigned su[16];                 // my 4 rows x 4 slots
    #pragma unroll
    for (int p = 0; p < 4; ++p) {
        union { uint4 v; unsigned a[4]; } u;
        u.v = *(const uint4*)&pslot_g[(grp << 5) + (p << 10) + (l8 << 2)];
        #pragma unroll
        for (int e = 0; e < 4; ++e) su[p * 4 + e] = u.a[e];
    }
    const float b3v = b3[0];

    for (int t2 = tid; t2 < (NUMK * ASTRIDE) / 8; t2 += 256)
        *(s8*)&Ab[t2 * 8] = (s8)0;
    {   // weights: coalesced float2 (8B alignment holds for every row)
        *(float2*)&wshp[tid * 2]       = *(const float2*)&rowp[NUMK + tid * 2];
        *(float2*)&wshp[512 + tid * 2] = *(const float2*)&rowp[NUMK + 512 + tid * 2];
    }
    if (tid == 0) { wshp[WSELF] = 1.0f; wshp[WPAD] = 0.0f; }
    if (tid < NUMK) pbuf[tid] = rowp[tid];
    for (int t2 = tid; t2 < HID * HID; t2 += 256) {
        const int k = t2 >> 5, n = t2 & 31;
        W2T[n * A1STRIDE + k] = (short)f2bf(W2[t2]);
    }
    if (tid < HID) {
        w1s[tid] = W1[tid]; b1s[tid] = b1[tid];
        b2s[tid] = b2[tid]; w3s[tid] = W3[tid];
    }
    __syncthreads();                                   // B1

    // ---- P3: merge duplicate weights FIRST (unique targets per pass) ----
    #pragma unroll 1
    for (int pass = 0; pass < NPASS; ++pass) {
        const unsigned c = dcnt_g[pass];               // uniform scalar load
        if (c == 0u) continue;
        if ((unsigned)tid < c) {
            const unsigned e = dent_g[(pass << 7) + tid];
            wshp[e & 0x7FFu] += wshp[(e >> 11) & 0x7FFu];
        }
        __syncthreads();
    }
    __syncthreads();                                   // B1b

    // ---- P2: deg -> dinv (merged weights over unique slots) ----
    #pragma unroll
    for (int p = 0; p < 4; ++p) {
        float d = 0.f;
        #pragma unroll
        for (int e = 0; e < 4; ++e) d += wshp[(su[p * 4 + e] >> 7) & 0x7FFu];
        d += __shfl_xor(d, 1, 8);
        d += __shfl_xor(d, 2, 8);
        d += __shfl_xor(d, 4, 8);
        if (l8 == 0) degv[grp + (p << 5)] = rsqrtf(d);  // deg >= 1 (self w=1)
    }
    __syncthreads();                                   // B2

    // ---- P4: norms -> Â bf16 + a0 = Â·p (fp32, shfl); nv kept in regs ----
    float nvr[16];
    #pragma unroll
    for (int p = 0; p < 4; ++p) {
        const int r = grp + (p << 5);
        const float dr = degv[r];
        float acc = 0.f;
        #pragma unroll
        for (int e = 0; e < 4; ++e) {
            const unsigned u = su[p * 4 + e];
            const int s = (int)(u & 127u);
            float nv = 0.f;
            if (u >> 18) {                             // primary slot
                nv = dr * degv[s] * wshp[(u >> 7) & 0x7FFu];
                Ab[r * ASTRIDE + s] = (short)f2bf(nv);
            }
            nvr[p * 4 + e] = nv;
            acc = fmaf(nv, pbuf[s], acc);
        }
        acc += __shfl_xor(acc, 1, 8);
        acc += __shfl_xor(acc, 2, 8);
        acc += __shfl_xor(acc, 4, 8);
        if (l8 == 0) a0s[r] = acc;
    }
    __syncthreads();                                   // B4

    // ---- P6: a1 = Â @ x1, x1[k][j] = relu(a0[k]*w1[j]+b1[j]) on the fly ----
    const int wv = tid >> 6;          // wave 0..3 -> rows [32wv, 32wv+32)
    const int l  = tid & 15;          // n index within 16-tile
    const int q  = (tid & 63) >> 4;   // quad 0..3 -> k-chunk / C-row group
    f4 acc[2][2] = {{{0.f,0.f,0.f,0.f},{0.f,0.f,0.f,0.f}},
                    {{0.f,0.f,0.f,0.f},{0.f,0.f,0.f,0.f}}};
    {
        const float w1a = w1s[l],      b1a = b1s[l];
        const float w1b = w1s[l + 16], b1b = b1s[l + 16];
        #pragma unroll
        for (int ks = 0; ks < 4; ++ks) {
            const int kb = 32 * ks + 8 * q;
            const s8 Am0 = *(const s8*)&Ab[(32 * wv      + l) * ASTRIDE + kb];
            const s8 Am1 = *(const s8*)&Ab[(32 * wv + 16 + l) * ASTRIDE + kb];
            const fl4 p0 = *(const fl4*)&a0s[kb];
            const fl4 p1 = *(const fl4*)&a0s[kb + 4];
            union { s8 v; unsigned u[4]; } B0, B1;
            #pragma unroll
            for (int e = 0; e < 4; ++e) {
                const float a0e = (e < 2) ? p0[2*e]     : p1[2*e - 4];
                const float a1e = (e < 2) ? p0[2*e + 1] : p1[2*e - 3];
                float xa0 = fmaf(a0e, w1a, b1a); xa0 = fmaxf(xa0, 0.f);
                float xa1 = fmaf(a1e, w1a, b1a); xa1 = fmaxf(xa1, 0.f);
                float xb0 = fmaf(a0e, w1b, b1b); xb0 = fmaxf(xb0, 0.f);
                float xb1 = fmaf(a1e, w1b, b1b); xb1 = fmaxf(xb1, 0.f);
                B0.u[e] = (unsigned)f2bf(xa0) | ((unsigned)f2bf(xa1) << 16);
                B1.u[e] = (unsigned)f2bf(xb0) | ((unsigned)f2bf(xb1) << 16);
            }
            acc[0][0] = __builtin_amdgcn_mfma_f32_16x16x32_bf16(Am0, B0.v, acc[0][0], 0, 0, 0);
            acc[0][1] = __builtin_amdgcn_mfma_f32_16x16x32_bf16(Am0, B1.v, acc[0][1], 0, 0, 0);
            acc[1][0] = __builtin_amdgcn_mfma_f32_16x16x32_bf16(Am1, B0.v, acc[1][0], 0, 0, 0);
            acc[1][1] = __builtin_amdgcn_mfma_f32_16x16x32_bf16(Am1, B1.v, acc[1][1], 0, 0, 0);
        }
    }

    // ---- P5': a1 (C layout) -> LDS bf16 (own wave's rows; wave-local order) ----
    #pragma unroll
    for (int mt = 0; mt < 2; ++mt)
        #pragma unroll
        for (int nt = 0; nt < 2; ++nt)
            #pragma unroll
            for (int r = 0; r < 4; ++r) {
                const int i = 32 * wv + 16 * mt + 4 * q + r;
                const int j = 16 * nt + l;
                a1bf[i * A1STRIDE + j] = (short)f2bf(acc[mt][nt][r]);
            }

    // ---- P7: x2 = relu(a1 @ W2 + b2); s = x2 @ W3 via shfl; sbuf = degv ----
    float* sbuf = degv;              // dinv dead after P4 (B4 separates)
    {
        f4 ac2[2][2] = {{{0.f,0.f,0.f,0.f},{0.f,0.f,0.f,0.f}},
                        {{0.f,0.f,0.f,0.f},{0.f,0.f,0.f,0.f}}};
        const s8 A0  = *(const s8*)&a1bf[(32 * wv      + l) * A1STRIDE + 8 * q];
        const s8 A1  = *(const s8*)&a1bf[(32 * wv + 16 + l) * A1STRIDE + 8 * q];
        const s8 Bw0 = *(const s8*)&W2T[(l)      * A1STRIDE + 8 * q];
        const s8 Bw1 = *(const s8*)&W2T[(16 + l) * A1STRIDE + 8 * q];
        ac2[0][0] = __builtin_amdgcn_mfma_f32_16x16x32_bf16(A0, Bw0, ac2[0][0], 0, 0, 0);
        ac2[0][1] = __builtin_amdgcn_mfma_f32_16x16x32_bf16(A0, Bw1, ac2[0][1], 0, 0, 0);
        ac2[1][0] = __builtin_amdgcn_mfma_f32_16x16x32_bf16(A1, Bw0, ac2[1][0], 0, 0, 0);
        ac2[1][1] = __builtin_amdgcn_mfma_f32_16x16x32_bf16(A1, Bw1, ac2[1][1], 0, 0, 0);

        const float b2a = b2s[l], b2b = b2s[l + 16];
        const float w3a = w3s[l], w3b = w3s[l + 16];
        #pragma unroll
        for (int mt = 0; mt < 2; ++mt)
            #pragma unroll
            for (int r = 0; r < 4; ++r) {
                const float v0 = fmaxf(ac2[mt][0][r] + b2a, 0.f);
                const float v1 = fmaxf(ac2[mt][1][r] + b2b, 0.f);
                float sv = v0 * w3a + v1 * w3b;
                #pragma unroll
                for (int m = 1; m < 16; m <<= 1) sv += __shfl_xor(sv, m, 16);
                if (l == 0) sbuf[32 * wv + 16 * mt + 4 * q + r] = sv;
            }
    }
    __syncthreads();                                   // B5

    // ---- P8: out = Â·s (fp32, shfl; norms from registers) ----
    #pragma unroll
    for (int p = 0; p < 4; ++p) {
        const int r = grp + (p << 5);
        float acc8 = 0.f;
        #pragma unroll
        for (int e = 0; e < 4; ++e)
            acc8 = fmaf(nvr[p * 4 + e], sbuf[su[p * 4 + e] & 127u], acc8);
        acc8 += __shfl_xor(acc8, 1, 8);
        acc8 += __shfl_xor(acc8, 2, 8);
        acc8 += __shfl_xor(acc8, 4, 8);
        if (l8 == 0) out[(size_t)blockIdx.x * NUMK + r] = acc8 + b3v;
    }
}

extern "C" void kernel_launch(void* const* d_in, const int* in_sizes, int n_in,
                              void* d_out, int out_size, void* d_ws, size_t ws_size,
                              hipStream_t stream) {
    const float* Hx = (const float*)d_in[0];
    const int*   ei = (const int*)d_in[1];
    const float* W1 = (const float*)d_in[2];
    const float* b1 = (const float*)d_in[3];
    const float* W2 = (const float*)d_in[4];
    const float* b2 = (const float*)d_in[5];
    const float* W3 = (const float*)d_in[6];
    const float* b3 = (const float*)d_in[7];
    float* out = (float*)d_out;

    unsigned* pslot = (unsigned*)d_ws;                 // [NPS]
    unsigned* dcnt  = pslot + NPS;                     // [NPASS]
    unsigned* dent  = dcnt + NPASS;                    // [NPASS*128]

    build_csr_kernel<<<1, 1024, 0, stream>>>(ei, pslot, dcnt, dent);
    gcn_main_kernel<<<NB, 256, 0, stream>>>(Hx, W1, b1, W2, b2, W3, b3,
                                            pslot, dcnt, dent, out);
}

// Round 7
// 109.956 us; speedup vs baseline: 1.3606x; 1.1041x over previous
//
#include <hip/hip_runtime.h>
#include <hip/hip_bf16.h>

#define NB    2048
#define NUMK  128
#define NE    1024
#define HID   32
#define ROWLEN (NUMK + NE + 2)
#define CAP   32                 // padded slots per row (unique srcs + self)
#define NPS   (NUMK * CAP)       // 4096
#define ASTRIDE 136              // bf16 elems per Â/x1T row (128 + 8 pad)
#define A1STRIDE 40              // bf16 elems per a1/W2T row (32 + 8 pad)
#define WSELF 1024               // widx of self-loop weight (1.0)
#define WPAD  1025               // widx of pad weight (0.0)
#define WVBASE 1026              // first vslot (chained dup merges)
#define MAXV  16
#define WTOT  (WVBASE + MAXV)    // 1042 floats

// slot encoding: src(7) | widx(11)<<7 | widx2(11)<<18 | prim(1)<<29
//   slot weight = wshp[widx] + wshp[widx2]  (widx2 = WPAD if none)
//   >=3 edges on one (dst,src): widx2 -> vslot, computed by tiny serial prepass
// vmeta: [0] = vcnt; [1+v] = a(11) | b(11)<<11  (wshp[WVBASE+v] = wshp[a]+wshp[b])

using s8  = __attribute__((ext_vector_type(8))) short;   // 8 bf16 = 16 B
using f4  = __attribute__((ext_vector_type(4))) float;
using fl4 = __attribute__((ext_vector_type(4))) float;

static __device__ __forceinline__ unsigned short f2bf(float f) {
    unsigned u = __float_as_uint(f);
    unsigned r = (u + 0x7fffu + ((u >> 16) & 1u)) >> 16;   // RNE
    return (unsigned short)r;
}

// ---------------------------------------------------------------------------
// Setup (once): CSR by dst, per-row dedup into (widx, widx2 [, vslot chain]).
// ---------------------------------------------------------------------------
__global__ __launch_bounds__(1024) void build_csr_kernel(
    const int* __restrict__ ei,
    unsigned* __restrict__ pslot_g,    // [NPS]
    unsigned* __restrict__ vmeta_g)    // [1 + MAXV]
{
    __shared__ unsigned cnt[NUMK], roff[NUMK + 1], cur[NUMK], incl[NUMK];
    __shared__ unsigned pk[NE];
    __shared__ unsigned psl[NUMK][CAP];
    __shared__ unsigned vc;
    const int t = threadIdx.x;

    if (t < NUMK) cnt[t] = 0u;
    if (t == 0) vc = 0u;
    __syncthreads();
    const int dst = ei[NE + t] & (NUMK - 1);
    atomicAdd(&cnt[dst], 1u);
    __syncthreads();

    if (t < NUMK) {                              // exclusive scan (2 wave scans)
        unsigned v = cnt[t];
        #pragma unroll
        for (int d = 1; d < 64; d <<= 1) {
            unsigned u = __shfl_up(v, d, 64);
            if ((t & 63) >= d) v += u;
        }
        incl[t] = v;
    }
    __syncthreads();
    if (t < NUMK) {
        const unsigned base = (t >= 64) ? incl[63] : 0u;
        const unsigned off  = base + incl[t] - cnt[t];
        roff[t] = off; cur[t] = off;
    }
    if (t == 0) roff[NUMK] = (unsigned)NE;
    __syncthreads();

    {
        const int src = ei[t] & (NUMK - 1);
        const unsigned pos = atomicAdd(&cur[dst], 1u);
        pk[pos] = (unsigned)src | ((unsigned)t << 16);
    }
    __syncthreads();

    if (t < NUMK) {
        int np = 0;
        auto addOrMerge = [&](unsigned s, unsigned eid) {
            int j = -1;
            for (int i = 0; i < np; ++i)
                if ((psl[t][i] & 127u) == s) { j = i; break; }
            if (j >= 0) {
                const unsigned slot = psl[t][j];
                const unsigned w2 = (slot >> 18) & 0x7FFu;
                if (w2 == (unsigned)WPAD) {
                    psl[t][j] = (slot & ~(0x7FFu << 18)) | (eid << 18);
                } else {
                    const unsigned v = atomicAdd(&vc, 1u);
                    if (v < (unsigned)MAXV) {
                        vmeta_g[1 + v] = w2 | (eid << 11);
                        psl[t][j] = (slot & ~(0x7FFu << 18))
                                  | (((unsigned)WVBASE + v) << 18);
                    }
                }
            } else if (np < CAP) {
                psl[t][np++] = s | (eid << 7)
                             | ((unsigned)WPAD << 18) | (1u << 29);
            }
        };
        const unsigned k0 = roff[t], k1 = roff[t + 1];
        for (unsigned k = k0; k < k1; ++k)
            addOrMerge(pk[k] & 127u, pk[k] >> 16);
        addOrMerge((unsigned)t, (unsigned)WSELF);        // self-loop, w = 1
        for (int i = np; i < CAP; ++i)                   // pads: w = 0, prim = 0
            psl[t][i] = ((unsigned)WPAD << 7) | ((unsigned)WPAD << 18);
    }
    __syncthreads();

    for (int i = t; i < NPS; i += 1024)
        pslot_g[i] = psl[i >> 5][i & 31];
    if (t == 0) vmeta_g[0] = (vc <= (unsigned)MAXV) ? vc : (unsigned)MAXV;
}

// ---------------------------------------------------------------------------
// Main: one block (256 thr = 4 waves) per graph. ~36.5 KB LDS -> 4 blocks/CU.
// Â processed as two 64-row panels in one 17.4 KB buffer; x1T materialized
// once (B-frags become ds_read_b128); x1T/a1bf share one union region.
// ---------------------------------------------------------------------------
__global__ __launch_bounds__(256) void gcn_main_kernel(
    const float* __restrict__ Hx,
    const float* __restrict__ W1, const float* __restrict__ b1,
    const float* __restrict__ W2, const float* __restrict__ b2,
    const float* __restrict__ W3, const float* __restrict__ b3,
    const unsigned* __restrict__ pslot_g,
    const unsigned* __restrict__ vmeta_g,
    float* __restrict__ out)
{
    __shared__ __align__(16) short Ab[64 * ASTRIDE];    // 17408 B (Â panel)
    __shared__ __align__(16) short uni[5120];           // 10240 B (x1T, then a1bf)
    __shared__ __align__(16) float wshp[WTOT];          //  4168 B
    __shared__ __align__(16) short W2T[HID * A1STRIDE]; //  2560 B
    __shared__ float pbuf[NUMK], degv[NUMK], a0s[NUMK]; //  1536 B
    __shared__ float w1s[HID], b1s[HID], b2s[HID], w3s[HID];   // 512 B
    // total ~36.5 KB -> 4 blocks/CU

    const int tid = threadIdx.x;
    const int grp = tid >> 3, l8 = tid & 7;      // 8 lanes per row group
    const int wv = tid >> 6, l = tid & 15, q = (tid & 63) >> 4;
    const float* rowp = Hx + (size_t)blockIdx.x * ROWLEN;

    // ---- P0: global loads first, then LDS staging ----
    unsigned su[16];                 // 4 rows x 4 slots, regs for whole kernel
    #pragma unroll
    for (int p = 0; p < 4; ++p) {
        union { uint4 v; unsigned a[4]; } u;
        u.v = *(const uint4*)&pslot_g[(grp << 5) + (p << 10) + (l8 << 2)];
        #pragma unroll
        for (int e = 0; e < 4; ++e) su[p * 4 + e] = u.a[e];
    }
    const float b3v = b3[0];
    const unsigned vcnt = vmeta_g[0];

    for (int t2 = tid; t2 < (64 * ASTRIDE) / 8; t2 += 256)
        *(s8*)&Ab[t2 * 8] = (s8)0;                       // zero panel A
    *(float2*)&wshp[tid * 2]       = *(const float2*)&rowp[NUMK + tid * 2];
    *(float2*)&wshp[512 + tid * 2] = *(const float2*)&rowp[NUMK + 512 + tid * 2];
    if (tid == 0) { wshp[WSELF] = 1.0f; wshp[WPAD] = 0.0f; }
    if (tid < NUMK) pbuf[tid] = rowp[tid];
    for (int t2 = tid; t2 < HID * HID; t2 += 256) {
        const int k = t2 >> 5, n = t2 & 31;
        W2T[n * A1STRIDE + k] = (short)f2bf(W2[t2]);
    }
    if (tid < HID) {
        w1s[tid] = W1[tid]; b1s[tid] = b1[tid];
        b2s[tid] = b2[tid]; w3s[tid] = W3[tid];
    }
    __syncthreads();                                   // B1

    // ---- vslot prepass (chained >=3 dups; uniform-skip, usually empty) ----
    if (vcnt) {
        if (tid == 0) {
            for (unsigned v = 0; v < vcnt; ++v) {
                const unsigned e = vmeta_g[1 + v];
                wshp[WVBASE + v] = wshp[e & 0x7FFu] + wshp[(e >> 11) & 0x7FFu];
            }
        }
        __syncthreads();
    }

    // ---- P2: merged slot weights (regs) + deg -> dinv ----
    float wr[16];
    #pragma unroll
    for (int p = 0; p < 4; ++p) {
        float d = 0.f;
        #pragma unroll
        for (int e = 0; e < 4; ++e) {
            const int i = p * 4 + e;
            const unsigned u = su[i];
            wr[i] = wshp[(u >> 7) & 0x7FFu] + wshp[(u >> 18) & 0x7FFu];
            d += wr[i];
        }
        d += __shfl_xor(d, 1, 8);
        d += __shfl_xor(d, 2, 8);
        d += __shfl_xor(d, 4, 8);
        if (l8 == 0) degv[grp + (p << 5)] = rsqrtf(d);   // deg >= 1 (self w=1)
    }
    __syncthreads();                                   // B2

    // ---- P4: norms (regs) + panel-A scatter + a0 = Â·p ----
    float nvr[16];
    #pragma unroll
    for (int p = 0; p < 4; ++p) {
        const int r = grp + (p << 5);
        const float dr = degv[r];
        float acc = 0.f;
        #pragma unroll
        for (int e = 0; e < 4; ++e) {
            const int i = p * 4 + e;
            const unsigned u = su[i];
            const int s = (int)(u & 127u);
            const float nv = (u >> 29) ? dr * degv[s] * wr[i] : 0.f;
            if ((u >> 29) && p < 2)                      // panel A rows 0..63
                Ab[r * ASTRIDE + s] = (short)f2bf(nv);
            nvr[i] = nv;
            acc = fmaf(nv, pbuf[s], acc);
        }
        acc += __shfl_xor(acc, 1, 8);
        acc += __shfl_xor(acc, 2, 8);
        acc += __shfl_xor(acc, 4, 8);
        if (l8 == 0) a0s[r] = acc;
    }
    __syncthreads();                                   // B3

    // ---- x1T build: x1T[j][k] = relu(a0[k]*w1[j]+b1[j]), bf16, stride 136 ----
    short* x1T = uni;
    {
        const int jj = tid >> 3, k0 = (tid & 7) << 4;
        const float w1j = w1s[jj], b1j = b1s[jj];
        float tmp[16];
        #pragma unroll
        for (int c = 0; c < 4; ++c) {
            const fl4 av = *(const fl4*)&a0s[k0 + 4 * c];
            #pragma unroll
            for (int e = 0; e < 4; ++e) tmp[c * 4 + e] = av[e];
        }
        union { unsigned u[8]; s8 v2[2]; } P;
        #pragma unroll
        for (int h = 0; h < 8; ++h) {
            const float x0 = fmaxf(fmaf(tmp[2 * h],     w1j, b1j), 0.f);
            const float x1 = fmaxf(fmaf(tmp[2 * h + 1], w1j, b1j), 0.f);
            P.u[h] = (unsigned)f2bf(x0) | ((unsigned)f2bf(x1) << 16);
        }
        *(s8*)&x1T[jj * ASTRIDE + k0]     = P.v2[0];
        *(s8*)&x1T[jj * ASTRIDE + k0 + 8] = P.v2[1];
    }
    __syncthreads();                                   // B4

    // ---- MFMA panel A: rows 16wv+l (acc[0]) ----
    f4 accm[2][2] = {{{0.f,0.f,0.f,0.f},{0.f,0.f,0.f,0.f}},
                     {{0.f,0.f,0.f,0.f},{0.f,0.f,0.f,0.f}}};
    {
        const int ar = (wv << 4) + l;
        #pragma unroll
        for (int ks = 0; ks < 4; ++ks) {
            const int kb = (ks << 5) + (q << 3);
            const s8 A  = *(const s8*)&Ab[ar * ASTRIDE + kb];
            const s8 B0 = *(const s8*)&x1T[l * ASTRIDE + kb];
            const s8 B1 = *(const s8*)&x1T[(16 + l) * ASTRIDE + kb];
            accm[0][0] = __builtin_amdgcn_mfma_f32_16x16x32_bf16(A, B0, accm[0][0], 0, 0, 0);
            accm[0][1] = __builtin_amdgcn_mfma_f32_16x16x32_bf16(A, B1, accm[0][1], 0, 0, 0);
        }
    }
    __syncthreads();                                   // B5 (panel-A reads done)

    // ---- panel B: zero + scatter (per-row same 8 lanes -> DS program order) ----
    {
        const int c0 = l8 << 4;                        // 16 cols = 32 B
        const s8 z = (s8)0;
        *(s8*)&Ab[grp * ASTRIDE + c0]            = z;
        *(s8*)&Ab[grp * ASTRIDE + c0 + 8]        = z;
        *(s8*)&Ab[(grp + 32) * ASTRIDE + c0]     = z;
        *(s8*)&Ab[(grp + 32) * ASTRIDE + c0 + 8] = z;
        #pragma unroll
        for (int p = 2; p < 4; ++p) {
            #pragma unroll
            for (int e = 0; e < 4; ++e) {
                const int i = p * 4 + e;
                const unsigned u = su[i];
                if (u >> 29) {
                    const int pr = grp + ((p - 2) << 5);   // panel row 0..63
                    Ab[pr * ASTRIDE + (int)(u & 127u)] = (short)f2bf(nvr[i]);
                }
            }
        }
    }
    __syncthreads();                                   // B6

    // ---- MFMA panel B: rows 64+16wv+l (acc[1]) ----
    {
        const int ar = (wv << 4) + l;
        #pragma unroll
        for (int ks = 0; ks < 4; ++ks) {
            const int kb = (ks << 5) + (q << 3);
            const s8 A  = *(const s8*)&Ab[ar * ASTRIDE + kb];
            const s8 B0 = *(const s8*)&x1T[l * ASTRIDE + kb];
            const s8 B1 = *(const s8*)&x1T[(16 + l) * ASTRIDE + kb];
            accm[1][0] = __builtin_amdgcn_mfma_f32_16x16x32_bf16(A, B0, accm[1][0], 0, 0, 0);
            accm[1][1] = __builtin_amdgcn_mfma_f32_16x16x32_bf16(A, B1, accm[1][1], 0, 0, 0);
        }
    }
    __syncthreads();                                   // B7 (x1T reads done)

    // ---- P5': a1 -> LDS bf16 (union region; own-wave rows 16wv & 64+16wv) ----
    short* a1bf = uni;
    #pragma unroll
    for (int P = 0; P < 2; ++P)
        #pragma unroll
        for (int nt = 0; nt < 2; ++nt)
            #pragma unroll
            for (int r = 0; r < 4; ++r) {
                const int i = (P << 6) + (wv << 4) + (q << 2) + r;
                const int j = (nt << 4) + l;
                a1bf[i * A1STRIDE + j] = (short)f2bf(accm[P][nt][r]);
            }

    // ---- P7: x2 = relu(a1@W2+b2); s = x2@W3 (same-wave rows; shfl reduce) ----
    float* sbuf = degv;                                // dinv dead after P4
    {
        f4 ac2[2][2] = {{{0.f,0.f,0.f,0.f},{0.f,0.f,0.f,0.f}},
                        {{0.f,0.f,0.f,0.f},{0.f,0.f,0.f,0.f}}};
        const s8 A0  = *(const s8*)&a1bf[((wv << 4) + l) * A1STRIDE + (q << 3)];
        const s8 A1  = *(const s8*)&a1bf[(64 + (wv << 4) + l) * A1STRIDE + (q << 3)];
        const s8 Bw0 = *(const s8*)&W2T[l * A1STRIDE + (q << 3)];
        const s8 Bw1 = *(const s8*)&W2T[(16 + l) * A1STRIDE + (q << 3)];
        ac2[0][0] = __builtin_amdgcn_mfma_f32_16x16x32_bf16(A0, Bw0, ac2[0][0], 0, 0, 0);
        ac2[0][1] = __builtin_amdgcn_mfma_f32_16x16x32_bf16(A0, Bw1, ac2[0][1], 0, 0, 0);
        ac2[1][0] = __builtin_amdgcn_mfma_f32_16x16x32_bf16(A1, Bw0, ac2[1][0], 0, 0, 0);
        ac2[1][1] = __builtin_amdgcn_mfma_f32_16x16x32_bf16(A1, Bw1, ac2[1][1], 0, 0, 0);

        const float b2a = b2s[l], b2b = b2s[l + 16];
        const float w3a = w3s[l], w3b = w3s[l + 16];
        #pragma unroll
        for (int mt = 0; mt < 2; ++mt)
            #pragma unroll
            for (int r = 0; r < 4; ++r) {
                const float v0 = fmaxf(ac2[mt][0][r] + b2a, 0.f);
                const float v1 = fmaxf(ac2[mt][1][r] + b2b, 0.f);
                float sv = v0 * w3a + v1 * w3b;
                #pragma unroll
                for (int m = 1; m < 16; m <<= 1) sv += __shfl_xor(sv, m, 16);
                if (l == 0) sbuf[(mt << 6) + (wv << 4) + (q << 2) + r] = sv;
            }
    }
    __syncthreads();                                   // B8

    // ---- P8: out = Â·s (norms from regs) ----
    #pragma unroll
    for (int p = 0; p < 4; ++p) {
        const int r = grp + (p << 5);
        float acc8 = 0.f;
        #pragma unroll
        for (int e = 0; e < 4; ++e)
            acc8 = fmaf(nvr[p * 4 + e], sbuf[su[p * 4 + e] & 127u], acc8);
        acc8 += __shfl_xor(acc8, 1, 8);
        acc8 += __shfl_xor(acc8, 2, 8);
        acc8 += __shfl_xor(acc8, 4, 8);
        if (l8 == 0) out[(size_t)blockIdx.x * NUMK + r] = acc8 + b3v;
    }
}

extern "C" void kernel_launch(void* const* d_in, const int* in_sizes, int n_in,
                              void* d_out, int out_size, void* d_ws, size_t ws_size,
                              hipStream_t stream) {
    const float* Hx = (const float*)d_in[0];
    const int*   ei = (const int*)d_in[1];
    const float* W1 = (const float*)d_in[2];
    const float* b1 = (const float*)d_in[3];
    const float* W2 = (const float*)d_in[4];
    const float* b2 = (const float*)d_in[5];
    const float* W3 = (const float*)d_in[6];
    const float* b3 = (const float*)d_in[7];
    float* out = (float*)d_out;

    unsigned* pslot = (unsigned*)d_ws;                 // [NPS]
    unsigned* vmeta = pslot + NPS;                     // [1 + MAXV]

    build_csr_kernel<<<1, 1024, 0, stream>>>(ei, pslot, vmeta);
    gcn_main_kernel<<<NB, 256, 0, stream>>>(Hx, W1, b1, W2, b2, W3, b3,
                                            pslot, vmeta, out);
}

// Round 8
// 106.651 us; speedup vs baseline: 1.4027x; 1.0310x over previous
//
#include <hip/hip_runtime.h>
#include <hip/hip_bf16.h>

#define NB    2048
#define NUMK  128
#define NE    1024
#define HID   32
#define ROWLEN (NUMK + NE + 2)
#define CAP   24                 // padded slots per row (unique srcs + self)
#define NPS   (NUMK * CAP)       // 3072
#define ASTRIDE 136              // bf16 elems per Â/x1T row (128 + 8 pad)
#define A1STRIDE 40              // bf16 elems per a1/W2T row (32 + 8 pad)
#define WSELF 1024               // widx of self-loop weight (1.0)
#define WPAD  1025               // widx of pad weight (0.0)
#define WVBASE 1026              // first vslot (chained dup merges)
#define MAXV  16
#define WTOT  (WVBASE + MAXV)

// slot encoding: src(7) | widx(11)<<7 | widx2(11)<<18 | prim(1)<<29
// pslot global layout (column-major for coalescing):
//   pslot_g[e*1024 + r*8 + l8] = psl[r][l8*3 + e],  e in [0,3)
// vmeta: [0]=vcnt; [1+v] = a(11) | b(11)<<11  (wshp[WVBASE+v]=wshp[a]+wshp[b])

using s8  = __attribute__((ext_vector_type(8))) short;   // 8 bf16 = 16 B
using f4  = __attribute__((ext_vector_type(4))) float;
using fl4 = __attribute__((ext_vector_type(4))) float;

static __device__ __forceinline__ unsigned short f2bf(float f) {
    unsigned u = __float_as_uint(f);
    unsigned r = (u + 0x7fffu + ((u >> 16) & 1u)) >> 16;   // RNE
    return (unsigned short)r;
}

// ---------------------------------------------------------------------------
// Setup (once): CSR by dst, per-row dedup into (widx, widx2 [, vslot chain]).
// ---------------------------------------------------------------------------
__global__ __launch_bounds__(1024) void build_csr_kernel(
    const int* __restrict__ ei,
    unsigned* __restrict__ pslot_g,    // [NPS] column-major (see above)
    unsigned* __restrict__ vmeta_g)    // [1 + MAXV]
{
    __shared__ unsigned cnt[NUMK], roff[NUMK + 1], cur[NUMK], incl[NUMK];
    __shared__ unsigned pk[NE];
    __shared__ unsigned psl[NUMK][CAP];
    __shared__ unsigned vc;
    const int t = threadIdx.x;

    if (t < NUMK) cnt[t] = 0u;
    if (t == 0) vc = 0u;
    __syncthreads();
    const int dst = ei[NE + t] & (NUMK - 1);
    atomicAdd(&cnt[dst], 1u);
    __syncthreads();

    if (t < NUMK) {                              // exclusive scan (2 wave scans)
        unsigned v = cnt[t];
        #pragma unroll
        for (int d = 1; d < 64; d <<= 1) {
            unsigned u = __shfl_up(v, d, 64);
            if ((t & 63) >= d) v += u;
        }
        incl[t] = v;
    }
    __syncthreads();
    if (t < NUMK) {
        const unsigned base = (t >= 64) ? incl[63] : 0u;
        const unsigned off  = base + incl[t] - cnt[t];
        roff[t] = off; cur[t] = off;
    }
    if (t == 0) roff[NUMK] = (unsigned)NE;
    __syncthreads();

    {
        const int src = ei[t] & (NUMK - 1);
        const unsigned pos = atomicAdd(&cur[dst], 1u);
        pk[pos] = (unsigned)src | ((unsigned)t << 16);
    }
    __syncthreads();

    if (t < NUMK) {
        int np = 0;
        auto addOrMerge = [&](unsigned s, unsigned eid) {
            int j = -1;
            for (int i = 0; i < np; ++i)
                if ((psl[t][i] & 127u) == s) { j = i; break; }
            if (j >= 0) {
                const unsigned slot = psl[t][j];
                const unsigned w2 = (slot >> 18) & 0x7FFu;
                if (w2 == (unsigned)WPAD) {
                    psl[t][j] = (slot & ~(0x7FFu << 18)) | (eid << 18);
                } else {
                    const unsigned v = atomicAdd(&vc, 1u);
                    if (v < (unsigned)MAXV) {
                        vmeta_g[1 + v] = w2 | (eid << 11);
                        psl[t][j] = (slot & ~(0x7FFu << 18))
                                  | (((unsigned)WVBASE + v) << 18);
                    }
                }
            } else if (np < CAP) {
                psl[t][np++] = s | (eid << 7)
                             | ((unsigned)WPAD << 18) | (1u << 29);
            }
        };
        const unsigned k0 = roff[t], k1 = roff[t + 1];
        for (unsigned k = k0; k < k1; ++k)
            addOrMerge(pk[k] & 127u, pk[k] >> 16);
        addOrMerge((unsigned)t, (unsigned)WSELF);        // self-loop, w = 1
        for (int i = np; i < CAP; ++i)                   // pads: w = 0, prim = 0
            psl[t][i] = ((unsigned)WPAD << 7) | ((unsigned)WPAD << 18);
    }
    __syncthreads();

    for (int i = t; i < NPS; i += 1024) {
        const int e = i >> 10, rem = i & 1023;
        const int r = rem >> 3, l8 = rem & 7;
        pslot_g[i] = psl[r][l8 * 3 + e];
    }
    if (t == 0) vmeta_g[0] = (vc <= (unsigned)MAXV) ? vc : (unsigned)MAXV;
}

// ---------------------------------------------------------------------------
// Main: one block (512 thr = 8 waves) per graph; ~36.5 KB LDS, 4 blocks/CU =
// 32 waves/CU. All phase work per thread is half of the R7 kernel; slot work
// is 6/thread (CAP=24). Dataflow identical to validated R7 kernel.
// ---------------------------------------------------------------------------
__global__ __launch_bounds__(512, 8) void gcn_main_kernel(
    const float* __restrict__ Hx,
    const float* __restrict__ W1, const float* __restrict__ b1,
    const float* __restrict__ W2, const float* __restrict__ b2,
    const float* __restrict__ W3, const float* __restrict__ b3,
    const unsigned* __restrict__ pslot_g,
    const unsigned* __restrict__ vmeta_g,
    float* __restrict__ out)
{
    __shared__ __align__(16) short Ab[64 * ASTRIDE];    // 17408 B (Â panel)
    __shared__ __align__(16) short uni[5120];           // 10240 B (x1T / a1bf)
    __shared__ __align__(16) float wshp[WTOT];          //  4168 B
    __shared__ __align__(16) short W2T[HID * A1STRIDE]; //  2560 B
    __shared__ float pbuf[NUMK], degv[NUMK], a0s[NUMK]; //  1536 B
    __shared__ float w1s[HID], b1s[HID], b2s[HID], w3s[HID];   // 512 B
    // total ~36.4 KB -> 4 blocks/CU (with 512 thr = 2048 thr/CU = max)

    const int tid = threadIdx.x;                 // 0..511
    const int grp = tid >> 3, l8 = tid & 7;      // 64 row groups x 8 lanes
    const int wv = tid >> 6, l = tid & 15, q = (tid & 63) >> 4;
    const int mt = wv >> 1, nt = wv & 1;         // MFMA tile assignment
    const float* rowp = Hx + (size_t)blockIdx.x * ROWLEN;

    // ---- P0: global loads first, then LDS staging ----
    unsigned su[6];                  // rows {grp, grp+64} x 3 slots
    #pragma unroll
    for (int p = 0; p < 2; ++p)
        #pragma unroll
        for (int e = 0; e < 3; ++e)
            su[p * 3 + e] = pslot_g[(e << 10) + (p << 9) + tid];   // coalesced
    const float b3v = b3[0];
    const unsigned vcnt = vmeta_g[0];

    for (int t2 = tid; t2 < (64 * ASTRIDE) / 8; t2 += 512)
        *(s8*)&Ab[t2 * 8] = (s8)0;                       // zero panel A
    *(float2*)&wshp[tid * 2] = *(const float2*)&rowp[NUMK + tid * 2];
    if (tid == 0) { wshp[WSELF] = 1.0f; wshp[WPAD] = 0.0f; }
    if (tid < NUMK) pbuf[tid] = rowp[tid];
    for (int t2 = tid; t2 < HID * HID; t2 += 512) {
        const int k = t2 >> 5, n = t2 & 31;
        W2T[n * A1STRIDE + k] = (short)f2bf(W2[t2]);
    }
    if (tid < HID) {
        w1s[tid] = W1[tid]; b1s[tid] = b1[tid];
        b2s[tid] = b2[tid]; w3s[tid] = W3[tid];
    }
    __syncthreads();                                   // B1

    // ---- vslot prepass (chained >=3 dups; usually empty) ----
    if (vcnt) {
        if (tid == 0) {
            for (unsigned v = 0; v < vcnt; ++v) {
                const unsigned e = vmeta_g[1 + v];
                wshp[WVBASE + v] = wshp[e & 0x7FFu] + wshp[(e >> 11) & 0x7FFu];
            }
        }
        __syncthreads();
    }

    // ---- P2: merged slot weights (into nvr) + deg -> dinv ----
    float nvr[6];
    #pragma unroll
    for (int p = 0; p < 2; ++p) {
        float d = 0.f;
        #pragma unroll
        for (int e = 0; e < 3; ++e) {
            const int i = p * 3 + e;
            const unsigned u = su[i];
            nvr[i] = wshp[(u >> 7) & 0x7FFu] + wshp[(u >> 18) & 0x7FFu];
            d += nvr[i];
        }
        d += __shfl_xor(d, 1, 8);
        d += __shfl_xor(d, 2, 8);
        d += __shfl_xor(d, 4, 8);
        if (l8 == 0) degv[grp + (p << 6)] = rsqrtf(d);   // deg >= 1 (self w=1)
    }
    __syncthreads();                                   // B2

    // ---- P4: norms (in nvr) + panel-A scatter + a0 = Â·p ----
    #pragma unroll
    for (int p = 0; p < 2; ++p) {
        const int r = grp + (p << 6);
        const float dr = degv[r];
        float acc = 0.f;
        #pragma unroll
        for (int e = 0; e < 3; ++e) {
            const int i = p * 3 + e;
            const unsigned u = su[i];
            const int s = (int)(u & 127u);
            const float nv = (u >> 29) ? dr * degv[s] * nvr[i] : 0.f;
            if ((u >> 29) && p == 0)                     // panel A rows 0..63
                Ab[r * ASTRIDE + s] = (short)f2bf(nv);
            nvr[i] = nv;
            acc = fmaf(nv, pbuf[s], acc);
        }
        acc += __shfl_xor(acc, 1, 8);
        acc += __shfl_xor(acc, 2, 8);
        acc += __shfl_xor(acc, 4, 8);
        if (l8 == 0) a0s[r] = acc;
    }
    __syncthreads();                                   // B3

    // ---- x1T build: x1T[j][k] = relu(a0[k]*w1[j]+b1[j]), bf16 ----
    short* x1T = uni;
    {
        const int jj = tid >> 4, k0 = (tid & 15) << 3;
        const float w1j = w1s[jj], b1j = b1s[jj];
        const fl4 av0 = *(const fl4*)&a0s[k0];
        const fl4 av1 = *(const fl4*)&a0s[k0 + 4];
        union { unsigned u[4]; s8 v; } P;
        #pragma unroll
        for (int h = 0; h < 4; ++h) {
            const float e0 = (h < 2) ? av0[2 * h]     : av1[2 * h - 4];
            const float e1 = (h < 2) ? av0[2 * h + 1] : av1[2 * h - 3];
            const float x0 = fmaxf(fmaf(e0, w1j, b1j), 0.f);
            const float x1 = fmaxf(fmaf(e1, w1j, b1j), 0.f);
            P.u[h] = (unsigned)f2bf(x0) | ((unsigned)f2bf(x1) << 16);
        }
        *(s8*)&x1T[jj * ASTRIDE + k0] = P.v;
    }
    __syncthreads();                                   // B4

    // ---- MFMA panel A: wave = (m-tile mt, n-tile nt) ----
    f4 accA = {0.f, 0.f, 0.f, 0.f}, accB = {0.f, 0.f, 0.f, 0.f};
    const int arow = (mt << 4) + l;                    // A row within panel
    const int brow = (nt << 4) + l;                    // x1T row (= a1 col)
    #pragma unroll
    for (int ks = 0; ks < 4; ++ks) {
        const int kb = (ks << 5) + (q << 3);
        const s8 A = *(const s8*)&Ab[arow * ASTRIDE + kb];
        const s8 B = *(const s8*)&x1T[brow * ASTRIDE + kb];
        accA = __builtin_amdgcn_mfma_f32_16x16x32_bf16(A, B, accA, 0, 0, 0);
    }
    __syncthreads();                                   // B5 (panel-A reads done)

    // ---- panel B: zero + scatter (row grp handled by its own 8 lanes) ----
    {
        const int c0 = l8 << 4;                        // cols l8*16..+15
        const s8 z = (s8)0;
        *(s8*)&Ab[grp * ASTRIDE + c0]     = z;
        *(s8*)&Ab[grp * ASTRIDE + c0 + 8] = z;
        #pragma unroll
        for (int e = 0; e < 3; ++e) {
            const unsigned u = su[3 + e];
            if (u >> 29)
                Ab[grp * ASTRIDE + (int)(u & 127u)] = (short)f2bf(nvr[3 + e]);
        }
    }
    __syncthreads();                                   // B6

    // ---- MFMA panel B ----
    #pragma unroll
    for (int ks = 0; ks < 4; ++ks) {
        const int kb = (ks << 5) + (q << 3);
        const s8 A = *(const s8*)&Ab[arow * ASTRIDE + kb];
        const s8 B = *(const s8*)&x1T[brow * ASTRIDE + kb];
        accB = __builtin_amdgcn_mfma_f32_16x16x32_bf16(A, B, accB, 0, 0, 0);
    }
    __syncthreads();                                   // B7 (x1T reads done)

    // ---- P5': a1 -> LDS bf16 (union region) ----
    short* a1bf = uni;
    #pragma unroll
    for (int r = 0; r < 4; ++r) {
        const int row = (mt << 4) + (q << 2) + r;
        const int col = (nt << 4) + l;
        a1bf[row * A1STRIDE + col]        = (short)f2bf(accA[r]);
        a1bf[(64 + row) * A1STRIDE + col] = (short)f2bf(accB[r]);
    }
    __syncthreads();                                   // B8

    // ---- P7: x2 = relu(a1@W2+b2); s = x2@W3 (16-wide shfl reduce) ----
    float* sbuf = degv;                                // dinv dead after P4
    {
        f4 ac20 = {0.f,0.f,0.f,0.f}, ac21 = {0.f,0.f,0.f,0.f};
        const s8 A0  = *(const s8*)&a1bf[((wv << 4) + l) * A1STRIDE + (q << 3)];
        const s8 Bw0 = *(const s8*)&W2T[l * A1STRIDE + (q << 3)];
        const s8 Bw1 = *(const s8*)&W2T[(16 + l) * A1STRIDE + (q << 3)];
        ac20 = __builtin_amdgcn_mfma_f32_16x16x32_bf16(A0, Bw0, ac20, 0, 0, 0);
        ac21 = __builtin_amdgcn_mfma_f32_16x16x32_bf16(A0, Bw1, ac21, 0, 0, 0);

        const float b2a = b2s[l], b2b = b2s[l + 16];
        const float w3a = w3s[l], w3b = w3s[l + 16];
        #pragma unroll
        for (int r = 0; r < 4; ++r) {
            const float v0 = fmaxf(ac20[r] + b2a, 0.f);
            const float v1 = fmaxf(ac21[r] + b2b, 0.f);
            float sv = v0 * w3a + v1 * w3b;
            #pragma unroll
            for (int m = 1; m < 16; m <<= 1) sv += __shfl_xor(sv, m, 16);
            if (l == 0) sbuf[(wv << 4) + (q << 2) + r] = sv;
        }
    }
    __syncthreads();                                   // B9

    // ---- P8: out = Â·s (norms from regs) ----
    #pragma unroll
    for (int p = 0; p < 2; ++p) {
        const int r = grp + (p << 6);
        float acc8 = 0.f;
        #pragma unroll
        for (int e = 0; e < 3; ++e)
            acc8 = fmaf(nvr[p * 3 + e], sbuf[su[p * 3 + e] & 127u], acc8);
        acc8 += __shfl_xor(acc8, 1, 8);
        acc8 += __shfl_xor(acc8, 2, 8);
        acc8 += __shfl_xor(acc8, 4, 8);
        if (l8 == 0) out[(size_t)blockIdx.x * NUMK + r] = acc8 + b3v;
    }
}

extern "C" void kernel_launch(void* const* d_in, const int* in_sizes, int n_in,
                              void* d_out, int out_size, void* d_ws, size_t ws_size,
                              hipStream_t stream) {
    const float* Hx = (const float*)d_in[0];
    const int*   ei = (const int*)d_in[1];
    const float* W1 = (const float*)d_in[2];
    const float* b1 = (const float*)d_in[3];
    const float* W2 = (const float*)d_in[4];
    const float* b2 = (const float*)d_in[5];
    const float* W3 = (const float*)d_in[6];
    const float* b3 = (const float*)d_in[7];
    float* out = (float*)d_out;

    unsigned* pslot = (unsigned*)d_ws;                 // [NPS]
    unsigned* vmeta = pslot + NPS;                     // [1 + MAXV]

    build_csr_kernel<<<1, 1024, 0, stream>>>(ei, pslot, vmeta);
    gcn_main_kernel<<<NB, 512, 0, stream>>>(Hx, W1, b1, W2, b2, W3, b3,
                                            pslot, vmeta, out);
}